// Round 1
// baseline (1041.837 us; speedup 1.0000x reference)
//
#include <hip/hip_runtime.h>
#include <hip/hip_bf16.h>
#include <math.h>

#define B_    2048
#define IND   20000
#define ENCN  512
#define BOTN  128
#define DECN  512
#define KP1   20480   // IND padded to 64*320
#define NP4   20096   // IND padded to 128*157
#define SPLITK 8
#define KSTEP1 40     // 8*40*64 = 20480
#define BNEPS 1e-5f

typedef __hip_bfloat16 bf16;
typedef __bf16 bf16x8 __attribute__((ext_vector_type(8)));
typedef float f32x4 __attribute__((ext_vector_type(4)));

__device__ __forceinline__ void gload_lds16(const bf16* g, bf16* l) {
  __builtin_amdgcn_global_load_lds(
      (const __attribute__((address_space(1))) void*)g,
      (__attribute__((address_space(3))) void*)l, 16, 0, 0);
}

// ---------------- row sums ----------------
__global__ void rowsum_k(const float* __restrict__ x, float* __restrict__ row_sum) {
  const int row = blockIdx.x;
  const float4* xr = (const float4*)(x + (size_t)row * IND);
  float s = 0.f;
  for (int i = threadIdx.x; i < IND / 4; i += 256) {
    float4 v = xr[i];
    s += (v.x + v.y) + (v.z + v.w);
  }
#pragma unroll
  for (int o = 32; o > 0; o >>= 1) s += __shfl_down(s, o, 64);
  __shared__ float ws4[4];
  if ((threadIdx.x & 63) == 0) ws4[threadIdx.x >> 6] = s;
  __syncthreads();
  if (threadIdx.x == 0) row_sum[row] = (ws4[0] + ws4[1]) + (ws4[2] + ws4[3]);
}

// ---------------- median + per-row scale ----------------
__global__ void median_scale_k(const float* __restrict__ row_sum,
                               float* __restrict__ sArr, float* __restrict__ invs) {
  __shared__ float v[B_];
  const int tid = threadIdx.x;  // 1024 threads
  v[tid] = row_sum[tid];
  v[tid + 1024] = row_sum[tid + 1024];
  __syncthreads();
  for (int k = 2; k <= B_; k <<= 1) {
    for (int j = k >> 1; j > 0; j >>= 1) {
      for (int i = tid; i < B_; i += 1024) {
        int ixj = i ^ j;
        if (ixj > i) {
          bool up = ((i & k) == 0);
          float a = v[i], b = v[ixj];
          if ((a > b) == up) { v[i] = b; v[ixj] = a; }
        }
      }
      __syncthreads();
    }
  }
  float med = 0.5f * (v[B_ / 2 - 1] + v[B_ / 2]);
  for (int i = tid; i < B_; i += 1024) {
    float rs = row_sum[i];
    sArr[i] = rs / med;
    invs[i] = med / rs;
  }
}

// ---------------- pass2: L = bf16(log1p(x*invs)), col sums/sumsq ----------------
__global__ void pass2_k(const float* __restrict__ x, const float* __restrict__ invs,
                        bf16* __restrict__ L, float* __restrict__ cs, float* __restrict__ cq) {
  const int c = blockIdx.x * 256 + threadIdx.x;   // 0..20479
  const int r0 = blockIdx.y * 128;
  const bool valid = (c < IND);
  float sum = 0.f, sq = 0.f;
  for (int r = r0; r < r0 + 128; ++r) {
    float lv = 0.f;
    if (valid) {
      float v = x[(size_t)r * IND + c];
      lv = log1pf(v * invs[r]);
      sum += lv; sq += lv * lv;
    }
    L[(size_t)r * KP1 + c] = __float2bfloat16(lv);
  }
  if (valid) { atomicAdd(&cs[c], sum); atomicAdd(&cq[c], sq); }
}

// ---------------- finalize BN0 (from atomic sums) ----------------
__global__ void finalize_bn_k(const float* __restrict__ cs, const float* __restrict__ cq,
                              const float* __restrict__ g, const float* __restrict__ b,
                              float* __restrict__ scale, float* __restrict__ shift, int C) {
  int c = blockIdx.x * 256 + threadIdx.x;
  if (c >= C) return;
  const float invN = 1.f / (float)B_;
  float mean = cs[c] * invN;
  float var = cq[c] * invN - mean * mean;
  float sc = g[c] * rsqrtf(var + BNEPS);
  scale[c] = sc;
  shift[c] = b[c] - mean * sc;
}

// ---------------- W' = bf16(enc_W * scale0), bias1 = enc_b + shift0 . enc_W^T ----------------
__global__ void prepw_k(const float* __restrict__ encW, const float* __restrict__ enc_b,
                        const float* __restrict__ scale0, const float* __restrict__ shift0,
                        bf16* __restrict__ Wp, float* __restrict__ bias1) {
  const int e = blockIdx.x;  // 512
  float local = 0.f;
  for (int j = threadIdx.x; j < KP1; j += 256) {
    float wv = 0.f;
    if (j < IND) {
      float wj = encW[(size_t)e * IND + j];
      wv = wj * scale0[j];
      local += shift0[j] * wj;
    }
    Wp[(size_t)e * KP1 + j] = __float2bfloat16(wv);
  }
#pragma unroll
  for (int o = 32; o > 0; o >>= 1) local += __shfl_down(local, o, 64);
  __shared__ float red[4];
  if ((threadIdx.x & 63) == 0) red[threadIdx.x >> 6] = local;
  __syncthreads();
  if (threadIdx.x == 0) bias1[e] = enc_b[e] + ((red[0] + red[1]) + (red[2] + red[3]));
}

// ---------------- m97-style bt GEMM: A[M][Kpad] bf16, B[N][Kpad] bf16 ----------------
// MODE 0: split-K partial store (out0 + z*B_*ldo), no bias
// MODE 1: sigmoid epilogue; MODE 2: exp + s*exp dual store; MODE 3: exp
template <int MODE>
__global__ __launch_bounds__(256, 2)
void gemm_bt(const bf16* __restrict__ A, const bf16* __restrict__ Bm,
             int Kpad, int ksteps,
             float* __restrict__ out0, float* __restrict__ out1,
             const float* __restrict__ bias, const float* __restrict__ sArr,
             int ldo, int Nlimit) {
  __shared__ __align__(16) bf16 As[128 * 64];
  __shared__ __align__(16) bf16 Bs[128 * 64];
  const int tid = threadIdx.x;
  const int wave = tid >> 6;
  const int lane = tid & 63;
  const int wr = wave >> 1, wc = wave & 1;
  const int m0 = blockIdx.x * 128;
  const int n0 = blockIdx.y * 128;
  const int kbeg = blockIdx.z * ksteps * 64;

  // staging: each wave fills 4KB of As and Bs per K-step via 4+4 global_load_lds
  const int srow = wave * 32 + (lane >> 3);
  const int scol = (lane & 7) * 8;
  const bf16* gA = A + (size_t)(m0 + srow) * Kpad + (kbeg + scol);
  const bf16* gB = Bm + (size_t)(n0 + srow) * Kpad + (kbeg + scol);
  bf16* lA = As + wave * 2048;
  bf16* lB = Bs + wave * 2048;

  f32x4 acc[4][4] = {};
  const int lrow = lane & 15;
  const int kgrp = (lane >> 4) * 8;

  for (int ks = 0; ks < ksteps; ++ks) {
#pragma unroll
    for (int i = 0; i < 4; ++i) {
      gload_lds16(gA + (size_t)(i * 8) * Kpad, lA + i * 512);
      gload_lds16(gB + (size_t)(i * 8) * Kpad, lB + i * 512);
    }
    gA += 64; gB += 64;
    __syncthreads();
#pragma unroll
    for (int kk = 0; kk < 64; kk += 32) {
      bf16x8 af[4], bfv[4];
#pragma unroll
      for (int m = 0; m < 4; ++m)
        af[m] = *(const bf16x8*)(As + (wr * 64 + m * 16 + lrow) * 64 + kk + kgrp);
#pragma unroll
      for (int n = 0; n < 4; ++n)
        bfv[n] = *(const bf16x8*)(Bs + (wc * 64 + n * 16 + lrow) * 64 + kk + kgrp);
#pragma unroll
      for (int m = 0; m < 4; ++m)
#pragma unroll
        for (int n = 0; n < 4; ++n)
          acc[m][n] = __builtin_amdgcn_mfma_f32_16x16x32_bf16(af[m], bfv[n], acc[m][n], 0, 0, 0);
    }
    __syncthreads();
  }

  float* o0 = out0;
  if (MODE == 0) o0 += (size_t)blockIdx.z * ((size_t)B_ * ldo);
  const int crow0 = m0 + wr * 64 + ((lane >> 4) << 2);
  const int ccol0 = n0 + wc * 64 + (lane & 15);
#pragma unroll
  for (int m = 0; m < 4; ++m) {
#pragma unroll
    for (int n = 0; n < 4; ++n) {
      const int gcol = ccol0 + n * 16;
#pragma unroll
      for (int r = 0; r < 4; ++r) {
        const int grow = crow0 + m * 16 + r;
        float t = acc[m][n][r];
        if (MODE == 0) {
          o0[(size_t)grow * ldo + gcol] = t;
        } else if (gcol < Nlimit) {
          t += bias[gcol];
          if (MODE == 1) {
            o0[(size_t)grow * ldo + gcol] = 1.f / (1.f + __expf(-t));
          } else if (MODE == 2) {
            float e = __expf(t);
            o0[(size_t)grow * ldo + gcol] = e;
            out1[(size_t)grow * ldo + gcol] = sArr[grow] * e;
          } else {
            o0[(size_t)grow * ldo + gcol] = __expf(t);
          }
        }
      }
    }
  }
}

// ---------------- split-K reduce + bias + relu -> C1 ----------------
__global__ void reduce1_k(const float* __restrict__ Cp, const float* __restrict__ bias1,
                          float* __restrict__ C1) {
  const size_t idx = (size_t)blockIdx.x * 256 + threadIdx.x;  // < 2048*512
  float t = 0.f;
#pragma unroll
  for (int z = 0; z < SPLITK; ++z) t += Cp[(size_t)z * (B_ * ENCN) + idx];
  t += bias1[idx & (ENCN - 1)];
  C1[idx] = fmaxf(t, 0.f);
}

// ---------------- small column stats (BN1 / BN2) ----------------
__global__ void colstats_k(const float* __restrict__ X, int R, int C,
                           const float* __restrict__ g, const float* __restrict__ b,
                           float* __restrict__ scale, float* __restrict__ shift) {
  const int cl = threadIdx.x & 63;
  const int rg = threadIdx.x >> 6;
  const int c = blockIdx.x * 64 + cl;
  float sum = 0.f, sq = 0.f;
  for (int r = rg; r < R; r += 4) {
    float v = X[(size_t)r * C + c];
    sum += v; sq += v * v;
  }
  __shared__ float ls[4][64], lq[4][64];
  ls[rg][cl] = sum; lq[rg][cl] = sq;
  __syncthreads();
  if (rg == 0) {
    sum = (ls[0][cl] + ls[1][cl]) + (ls[2][cl] + ls[3][cl]);
    sq = (lq[0][cl] + lq[1][cl]) + (lq[2][cl] + lq[3][cl]);
    float invN = 1.f / (float)R;
    float mean = sum * invN;
    float var = sq * invN - mean * mean;
    float sc = g[c] * rsqrtf(var + BNEPS);
    scale[c] = sc;
    shift[c] = b[c] - mean * sc;
  }
}

// ---------------- small fp32 tiled GEMM with fused input affine + relu ----------------
template <bool OUT_BF16>
__global__ void gemm_small(const float* __restrict__ A,
                           const float* __restrict__ scale, const float* __restrict__ shift,
                           const float* __restrict__ Wt, const float* __restrict__ bias,
                           float* __restrict__ outF, bf16* __restrict__ outB,
                           int M, int N, int K) {
  __shared__ float As[16][17], Bs[16][17];
  const int tx = threadIdx.x, ty = threadIdx.y;
  const int r = blockIdx.x * 16 + ty;
  const int n = blockIdx.y * 16 + tx;
  float acc = 0.f;
  for (int k0 = 0; k0 < K; k0 += 16) {
    As[ty][tx] = A[(size_t)r * K + k0 + tx] * scale[k0 + tx] + shift[k0 + tx];
    Bs[ty][tx] = Wt[(size_t)(blockIdx.y * 16 + ty) * K + k0 + tx];
    __syncthreads();
#pragma unroll
    for (int i = 0; i < 16; ++i) acc += As[ty][i] * Bs[tx][i];
    __syncthreads();
  }
  acc = fmaxf(acc + bias[n], 0.f);
  if (OUT_BF16) outB[(size_t)r * N + n] = __float2bfloat16(acc);
  else          outF[(size_t)r * N + n] = acc;
}

// ---------------- fp32 -> bf16 weight convert with row pad to NP4 ----------------
__global__ void cvt_o_k(const float* __restrict__ Wsrc, bf16* __restrict__ Wb) {
  const size_t idx = (size_t)blockIdx.x * 256 + threadIdx.x;  // < NP4*512
  const int e = (int)(idx >> 9);
  float v = (e < IND) ? Wsrc[idx] : 0.f;
  Wb[idx] = __float2bfloat16(v);
}

extern "C" void kernel_launch(void* const* d_in, const int* in_sizes, int n_in,
                              void* d_out, int out_size, void* d_ws, size_t ws_size,
                              hipStream_t stream) {
  const float* x     = (const float*)d_in[0];
  const float* bn0_g = (const float*)d_in[1];
  const float* bn0_b = (const float*)d_in[2];
  const float* enc_W = (const float*)d_in[3];
  const float* enc_b = (const float*)d_in[4];
  const float* bn1_g = (const float*)d_in[5];
  const float* bn1_b = (const float*)d_in[6];
  const float* bot_W = (const float*)d_in[7];
  const float* bot_b = (const float*)d_in[8];
  const float* bn2_g = (const float*)d_in[9];
  const float* bn2_b = (const float*)d_in[10];
  const float* dec_W = (const float*)d_in[11];
  const float* dec_b = (const float*)d_in[12];
  const float* o1_W  = (const float*)d_in[13];
  const float* o1_b  = (const float*)d_in[14];
  const float* o2_W  = (const float*)d_in[15];
  const float* o2_b  = (const float*)d_in[16];
  const float* o3_W  = (const float*)d_in[17];
  const float* o3_b  = (const float*)d_in[18];

  char* wsb = (char*)d_ws;
  size_t off = 0;
  auto alloc = [&](size_t bytes) -> void* {
    void* p = wsb + off;
    off = (off + bytes + 255) & ~(size_t)255;
    return p;
  };
  float* row_sum = (float*)alloc(B_ * 4);
  float* sArr    = (float*)alloc(B_ * 4);
  float* invs    = (float*)alloc(B_ * 4);
  float* colsum0 = (float*)alloc(IND * 4);
  float* colsq0  = (float*)alloc(IND * 4);
  float* scale0  = (float*)alloc(IND * 4);
  float* shift0  = (float*)alloc(IND * 4);
  float* bias1   = (float*)alloc(ENCN * 4);
  float* scale1  = (float*)alloc(ENCN * 4);
  float* shift1  = (float*)alloc(ENCN * 4);
  float* scale2  = (float*)alloc(BOTN * 4);
  float* shift2  = (float*)alloc(BOTN * 4);
  float* C1      = (float*)alloc((size_t)B_ * ENCN * 4);
  float* C2      = (float*)alloc((size_t)B_ * BOTN * 4);
  float* Cp      = (float*)alloc((size_t)SPLITK * B_ * ENCN * 4);
  bf16*  L       = (bf16*)alloc((size_t)B_ * KP1 * 2);
  bf16*  Wp      = (bf16*)alloc((size_t)ENCN * KP1 * 2);
  bf16*  h3      = (bf16*)alloc((size_t)B_ * DECN * 2);
  bf16*  wbf0    = (bf16*)alloc((size_t)NP4 * 512 * 2);
  bf16*  wbf1    = (bf16*)alloc((size_t)NP4 * 512 * 2);
  bf16*  wbf2    = (bf16*)alloc((size_t)NP4 * 512 * 2);

  // 1. row sums + median scales
  rowsum_k<<<B_, 256, 0, stream>>>(x, row_sum);
  median_scale_k<<<1, 1024, 0, stream>>>(row_sum, sArr, invs);

  // 2. L = bf16(log1p(x/s)), BN0 stats
  hipMemsetAsync(colsum0, 0, IND * 4, stream);
  hipMemsetAsync(colsq0, 0, IND * 4, stream);
  pass2_k<<<dim3(KP1 / 256, B_ / 128), 256, 0, stream>>>(x, invs, L, colsum0, colsq0);
  finalize_bn_k<<<(IND + 255) / 256, 256, 0, stream>>>(colsum0, colsq0, bn0_g, bn0_b,
                                                       scale0, shift0, IND);

  // 3. fold BN0 into encoder weights
  prepw_k<<<ENCN, 256, 0, stream>>>(enc_W, enc_b, scale0, shift0, Wp, bias1);

  // 4. GEMM1 (split-K=8) + reduce(+bias+relu) -> C1
  gemm_bt<0><<<dim3(B_ / 128, ENCN / 128, SPLITK), 256, 0, stream>>>(
      L, Wp, KP1, KSTEP1, Cp, nullptr, nullptr, nullptr, ENCN, ENCN);
  reduce1_k<<<(B_ * ENCN) / 256, 256, 0, stream>>>(Cp, bias1, C1);

  // 5. BN1 -> GEMM2 -> C2; BN2 -> GEMM3 -> h3 (bf16)
  colstats_k<<<ENCN / 64, 256, 0, stream>>>(C1, B_, ENCN, bn1_g, bn1_b, scale1, shift1);
  gemm_small<false><<<dim3(B_ / 16, BOTN / 16), dim3(16, 16), 0, stream>>>(
      C1, scale1, shift1, bot_W, bot_b, C2, nullptr, B_, BOTN, ENCN);
  colstats_k<<<BOTN / 64, 256, 0, stream>>>(C2, B_, BOTN, bn2_g, bn2_b, scale2, shift2);
  gemm_small<true><<<dim3(B_ / 16, DECN / 16), dim3(16, 16), 0, stream>>>(
      C2, scale2, shift2, dec_W, dec_b, nullptr, h3, B_, DECN, BOTN);

  // 6. convert output weights to bf16 (padded rows = 0)
  const int cvtg = (NP4 * 512) / 256;
  cvt_o_k<<<cvtg, 256, 0, stream>>>(o1_W, wbf0);
  cvt_o_k<<<cvtg, 256, 0, stream>>>(o2_W, wbf1);
  cvt_o_k<<<cvtg, 256, 0, stream>>>(o3_W, wbf2);

  // 7. output GEMMs with fused epilogues
  float* out = (float*)d_out;
  const size_t OFF = (size_t)B_ * IND;
  // pai = sigmoid(h3 @ o2_W.T + o2_b)
  gemm_bt<1><<<dim3(B_ / 128, NP4 / 128), 256, 0, stream>>>(
      h3, wbf1, 512, 8, out, nullptr, o2_b, nullptr, IND, IND);
  // M = exp(h3 @ o1_W.T + o1_b), M_loss = s * M
  gemm_bt<2><<<dim3(B_ / 128, NP4 / 128), 256, 0, stream>>>(
      h3, wbf0, 512, 8, out + OFF, out + 3 * OFF, o1_b, sArr, IND, IND);
  // theta = exp(h3 @ o3_W.T + o3_b)
  gemm_bt<3><<<dim3(B_ / 128, NP4 / 128), 256, 0, stream>>>(
      h3, wbf2, 512, 8, out + 2 * OFF, nullptr, o3_b, nullptr, IND, IND);
}

// Round 2
// 994.046 us; speedup vs baseline: 1.0481x; 1.0481x over previous
//
#include <hip/hip_runtime.h>
#include <hip/hip_bf16.h>
#include <math.h>

#define B_    2048
#define IND   20000
#define ENCN  512
#define BOTN  128
#define DECN  512
#define KP1   20480   // IND padded to 64*320
#define NP4   20096   // IND padded to 128*157
#define SPLITK 8
#define KSTEP1 40     // 8*40*64 = 20480
#define BNEPS 1e-5f

typedef __hip_bfloat16 bf16;
typedef __bf16 bf16x8 __attribute__((ext_vector_type(8)));
typedef float f32x4 __attribute__((ext_vector_type(4)));
typedef unsigned short u16;

__device__ __forceinline__ u16 f2bfu(float f) {
  __hip_bfloat16 h = __float2bfloat16(f);
  return *reinterpret_cast<u16*>(&h);
}

__device__ __forceinline__ void gload_lds16(const bf16* g, bf16* l) {
  __builtin_amdgcn_global_load_lds(
      (const __attribute__((address_space(1))) void*)g,
      (__attribute__((address_space(3))) void*)l, 16, 0, 0);
}

// ---------------- row sums ----------------
__global__ void rowsum_k(const float* __restrict__ x, float* __restrict__ row_sum) {
  const int row = blockIdx.x;
  const f32x4* xr = (const f32x4*)(x + (size_t)row * IND);
  float s = 0.f;
  for (int i = threadIdx.x; i < IND / 4; i += 256) {
    f32x4 v = xr[i];
    s += (v[0] + v[1]) + (v[2] + v[3]);
  }
#pragma unroll
  for (int o = 32; o > 0; o >>= 1) s += __shfl_down(s, o, 64);
  __shared__ float ws4[4];
  if ((threadIdx.x & 63) == 0) ws4[threadIdx.x >> 6] = s;
  __syncthreads();
  if (threadIdx.x == 0) row_sum[row] = (ws4[0] + ws4[1]) + (ws4[2] + ws4[3]);
}

// ---------------- median + per-row scale ----------------
__global__ void median_scale_k(const float* __restrict__ row_sum,
                               float* __restrict__ sArr, float* __restrict__ invs) {
  __shared__ float v[B_];
  const int tid = threadIdx.x;  // 1024 threads
  v[tid] = row_sum[tid];
  v[tid + 1024] = row_sum[tid + 1024];
  __syncthreads();
  for (int k = 2; k <= B_; k <<= 1) {
    for (int j = k >> 1; j > 0; j >>= 1) {
      for (int i = tid; i < B_; i += 1024) {
        int ixj = i ^ j;
        if (ixj > i) {
          bool up = ((i & k) == 0);
          float a = v[i], b = v[ixj];
          if ((a > b) == up) { v[i] = b; v[ixj] = a; }
        }
      }
      __syncthreads();
    }
  }
  float med = 0.5f * (v[B_ / 2 - 1] + v[B_ / 2]);
  for (int i = tid; i < B_; i += 1024) {
    float rs = row_sum[i];
    sArr[i] = rs / med;
    invs[i] = med / rs;
  }
}

// ---------------- pass2: L = bf16(log1p(x*invs)), partial col sums/sumsq ----------------
// grid (KP1/1024, 64), 256 thr; thread handles 4 cols x 32 rows
__global__ void pass2_k(const float* __restrict__ x, const float* __restrict__ invs,
                        bf16* __restrict__ L, float* __restrict__ part_s,
                        float* __restrict__ part_q) {
  const int c0 = (blockIdx.x * 256 + threadIdx.x) * 4;   // 0..20476
  const int rblk = blockIdx.y;
  const int r0 = rblk * 32;
  const bool valid = (c0 < IND);
  f32x4 sum = {0.f, 0.f, 0.f, 0.f}, sq = {0.f, 0.f, 0.f, 0.f};
  for (int r = r0; r < r0 + 32; ++r) {
    f32x4 lv = {0.f, 0.f, 0.f, 0.f};
    if (valid) {
      f32x4 v = *(const f32x4*)(x + (size_t)r * IND + c0);
      float iv = invs[r];
      lv[0] = log1pf(v[0] * iv); lv[1] = log1pf(v[1] * iv);
      lv[2] = log1pf(v[2] * iv); lv[3] = log1pf(v[3] * iv);
      sum += lv; sq += lv * lv;
    }
    ushort4 o;
    o.x = f2bfu(lv[0]); o.y = f2bfu(lv[1]); o.z = f2bfu(lv[2]); o.w = f2bfu(lv[3]);
    *(ushort4*)((u16*)L + (size_t)r * KP1 + c0) = o;
  }
  if (valid) {
    *(f32x4*)(part_s + (size_t)rblk * KP1 + c0) = sum;
    *(f32x4*)(part_q + (size_t)rblk * KP1 + c0) = sq;
  }
}

// ---------------- finalize BN0 from 64 partials ----------------
__global__ void finalize_bn_k(const float* __restrict__ part_s, const float* __restrict__ part_q,
                              const float* __restrict__ g, const float* __restrict__ b,
                              float* __restrict__ scale, float* __restrict__ shift) {
  int c = blockIdx.x * 256 + threadIdx.x;
  if (c >= IND) return;
  float s = 0.f, q = 0.f;
  for (int z = 0; z < 64; ++z) {
    s += part_s[(size_t)z * KP1 + c];
    q += part_q[(size_t)z * KP1 + c];
  }
  const float invN = 1.f / (float)B_;
  float mean = s * invN;
  float var = q * invN - mean * mean;
  float sc = g[c] * rsqrtf(var + BNEPS);
  scale[c] = sc;
  shift[c] = b[c] - mean * sc;
}

// ---------------- W' = bf16(enc_W * scale0), bias1 = enc_b + shift0 . enc_W^T ----------------
__global__ void prepw_k(const float* __restrict__ encW, const float* __restrict__ enc_b,
                        const float* __restrict__ scale0, const float* __restrict__ shift0,
                        bf16* __restrict__ Wp, float* __restrict__ bias1) {
  const int e = blockIdx.x;  // 512
  float local = 0.f;
  for (int j0 = threadIdx.x * 4; j0 < KP1; j0 += 1024) {
    ushort4 o;
    if (j0 < IND) {
      f32x4 w = *(const f32x4*)(encW + (size_t)e * IND + j0);
      f32x4 sc = *(const f32x4*)(scale0 + j0);
      f32x4 sh = *(const f32x4*)(shift0 + j0);
      local += sh[0] * w[0] + sh[1] * w[1] + sh[2] * w[2] + sh[3] * w[3];
      o.x = f2bfu(w[0] * sc[0]); o.y = f2bfu(w[1] * sc[1]);
      o.z = f2bfu(w[2] * sc[2]); o.w = f2bfu(w[3] * sc[3]);
    } else {
      o.x = 0; o.y = 0; o.z = 0; o.w = 0;
    }
    *(ushort4*)((u16*)Wp + (size_t)e * KP1 + j0) = o;
  }
#pragma unroll
  for (int o = 32; o > 0; o >>= 1) local += __shfl_down(local, o, 64);
  __shared__ float red[4];
  if ((threadIdx.x & 63) == 0) red[threadIdx.x >> 6] = local;
  __syncthreads();
  if (threadIdx.x == 0) bias1[e] = enc_b[e] + ((red[0] + red[1]) + (red[2] + red[3]));
}

// ---------------- 2-phase dbuf bt GEMM, swizzled LDS, vectorized epilogue ----------------
// A[M][Kpad] bf16, B[N][Kpad] bf16, C = A.B^T
// MODE 0: split-K partial f32x4 store; 1: sigmoid; 2: exp + s*exp dual; 3: exp
template <int MODE>
__global__ __launch_bounds__(256, 2)
void gemm_bt(const bf16* __restrict__ A, const bf16* __restrict__ Bm,
             int Kpad, int ksteps,
             float* __restrict__ out0, float* __restrict__ out1,
             const float* __restrict__ bias, const float* __restrict__ sArr,
             int ldo, int Nlimit) {
  __shared__ __align__(16) bf16 As[2][128 * 64];
  __shared__ __align__(16) bf16 Bs[2][128 * 64];
  const int tid = threadIdx.x;
  const int wave = tid >> 6;
  const int lane = tid & 63;
  const int wr = wave >> 1, wc = wave & 1;
  const int m0 = blockIdx.x * 128;
  const int n0 = blockIdx.y * 128;
  const int kbeg = blockIdx.z * ksteps * 64;

  // staging: wave fills rows [wave*32, wave*32+32) of both tiles per K-step.
  // LDS dest is linear (gload_lds requirement); source column chunk is
  // pre-swizzled: lds row&7 == lane>>3, so chunk = (lane&7) ^ (lane>>3).
  const int srow = wave * 32 + (lane >> 3);
  const int scol = ((lane & 7) ^ (lane >> 3)) * 8;
  const bf16* gA = A + (size_t)(m0 + srow) * Kpad + kbeg + scol;
  const bf16* gB = Bm + (size_t)(n0 + srow) * Kpad + kbeg + scol;
  const int lbase = wave * 2048;

  f32x4 acc[4][4] = {};
  const int lrow = lane & 15;
  const int swz = lrow & 7;
  const int kc_lo = lane >> 4;  // 0..3

  auto STAGE = [&](int ks, int buf) {
    const bf16* ga = gA + (size_t)ks * 64;
    const bf16* gb = gB + (size_t)ks * 64;
#pragma unroll
    for (int i = 0; i < 4; ++i) {
      gload_lds16(ga + (size_t)(i * 8) * Kpad, &As[buf][lbase + i * 512]);
      gload_lds16(gb + (size_t)(i * 8) * Kpad, &Bs[buf][lbase + i * 512]);
    }
  };

  STAGE(0, 0);
  asm volatile("s_waitcnt vmcnt(0)" ::: "memory");
  __builtin_amdgcn_s_barrier();

  int cur = 0;
  for (int ks = 0; ks < ksteps; ++ks) {
    if (ks + 1 < ksteps) STAGE(ks + 1, cur ^ 1);   // issue next tile early
#pragma unroll
    for (int kk = 0; kk < 64; kk += 32) {
      bf16x8 af[4], bfv[4];
      const int kc = (kk >> 3) + kc_lo;
#pragma unroll
      for (int m = 0; m < 4; ++m) {
        const int row = wr * 64 + m * 16 + lrow;
        af[m] = *(const bf16x8*)(&As[cur][row * 64 + ((kc ^ swz) << 3)]);
      }
#pragma unroll
      for (int n = 0; n < 4; ++n) {
        const int row = wc * 64 + n * 16 + lrow;
        bfv[n] = *(const bf16x8*)(&Bs[cur][row * 64 + ((kc ^ swz) << 3)]);
      }
#pragma unroll
      for (int m = 0; m < 4; ++m)
#pragma unroll
        for (int n = 0; n < 4; ++n)
          // swapped operands: lane holds C[m_base + (lane&15)][n_base + (lane>>4)*4 + reg]
          acc[m][n] = __builtin_amdgcn_mfma_f32_16x16x32_bf16(bfv[n], af[m], acc[m][n], 0, 0, 0);
    }
    if (ks + 1 < ksteps) {
      asm volatile("s_waitcnt vmcnt(0)" ::: "memory");  // next tile landed
      __builtin_amdgcn_s_barrier();                     // all reads of cur done
      cur ^= 1;
    }
  }

  float* o0 = out0;
  if (MODE == 0) o0 += (size_t)blockIdx.z * ((size_t)B_ * ldo);
  const int growb = m0 + wr * 64 + lrow;
  const int gcolb = n0 + wc * 64 + kc_lo * 4;
#pragma unroll
  for (int m = 0; m < 4; ++m) {
    const int grow = growb + m * 16;
    float srow_s = 0.f;
    if (MODE == 2) srow_s = sArr[grow];
#pragma unroll
    for (int n = 0; n < 4; ++n) {
      const int gcol = gcolb + n * 16;
      f32x4 v = acc[m][n];
      if (MODE == 0) {
        *(f32x4*)(&o0[(size_t)grow * ldo + gcol]) = v;
      } else if (gcol < Nlimit) {   // gcol%4==0 and Nlimit%4==0: whole-vector guard
        f32x4 bb = *(const f32x4*)(&bias[gcol]);
        f32x4 t = v + bb;
        f32x4 r;
        if (MODE == 1) {
#pragma unroll
          for (int j = 0; j < 4; ++j) r[j] = 1.f / (1.f + __expf(-t[j]));
          *(f32x4*)(&o0[(size_t)grow * ldo + gcol]) = r;
        } else if (MODE == 2) {
#pragma unroll
          for (int j = 0; j < 4; ++j) r[j] = __expf(t[j]);
          *(f32x4*)(&o0[(size_t)grow * ldo + gcol]) = r;
          f32x4 rl;
#pragma unroll
          for (int j = 0; j < 4; ++j) rl[j] = srow_s * r[j];
          *(f32x4*)(&out1[(size_t)grow * ldo + gcol]) = rl;
        } else {
#pragma unroll
          for (int j = 0; j < 4; ++j) r[j] = __expf(t[j]);
          *(f32x4*)(&o0[(size_t)grow * ldo + gcol]) = r;
        }
      }
    }
  }
}

// ---------------- split-K reduce + bias + relu -> C1 ----------------
__global__ void reduce1_k(const float* __restrict__ Cp, const float* __restrict__ bias1,
                          float* __restrict__ C1) {
  const size_t i4 = ((size_t)blockIdx.x * 256 + threadIdx.x) * 4;  // < 2048*512
  f32x4 t = {0.f, 0.f, 0.f, 0.f};
#pragma unroll
  for (int z = 0; z < SPLITK; ++z) t += *(const f32x4*)(Cp + (size_t)z * (B_ * ENCN) + i4);
  f32x4 bb = *(const f32x4*)(bias1 + (i4 & (ENCN - 1)));
  t += bb;
  f32x4 r;
#pragma unroll
  for (int j = 0; j < 4; ++j) r[j] = fmaxf(t[j], 0.f);
  *(f32x4*)(C1 + i4) = r;
}

// ---------------- small column stats (BN1 / BN2) ----------------
__global__ void colstats_k(const float* __restrict__ X, int R, int C,
                           const float* __restrict__ g, const float* __restrict__ b,
                           float* __restrict__ scale, float* __restrict__ shift) {
  const int cl = threadIdx.x & 63;
  const int rg = threadIdx.x >> 6;
  const int c = blockIdx.x * 64 + cl;
  float sum = 0.f, sq = 0.f;
  for (int r = rg; r < R; r += 4) {
    float v = X[(size_t)r * C + c];
    sum += v; sq += v * v;
  }
  __shared__ float ls[4][64], lq[4][64];
  ls[rg][cl] = sum; lq[rg][cl] = sq;
  __syncthreads();
  if (rg == 0) {
    sum = (ls[0][cl] + ls[1][cl]) + (ls[2][cl] + ls[3][cl]);
    sq = (lq[0][cl] + lq[1][cl]) + (lq[2][cl] + lq[3][cl]);
    float invN = 1.f / (float)R;
    float mean = sum * invN;
    float var = sq * invN - mean * mean;
    float sc = g[c] * rsqrtf(var + BNEPS);
    scale[c] = sc;
    shift[c] = b[c] - mean * sc;
  }
}

// ---------------- small fp32 tiled GEMM with fused input affine + relu ----------------
template <bool OUT_BF16>
__global__ void gemm_small(const float* __restrict__ A,
                           const float* __restrict__ scale, const float* __restrict__ shift,
                           const float* __restrict__ Wt, const float* __restrict__ bias,
                           float* __restrict__ outF, bf16* __restrict__ outB,
                           int M, int N, int K) {
  __shared__ float As[16][17], Bs[16][17];
  const int tx = threadIdx.x, ty = threadIdx.y;
  const int r = blockIdx.x * 16 + ty;
  const int n = blockIdx.y * 16 + tx;
  float acc = 0.f;
  for (int k0 = 0; k0 < K; k0 += 16) {
    As[ty][tx] = A[(size_t)r * K + k0 + tx] * scale[k0 + tx] + shift[k0 + tx];
    Bs[ty][tx] = Wt[(size_t)(blockIdx.y * 16 + ty) * K + k0 + tx];
    __syncthreads();
#pragma unroll
    for (int i = 0; i < 16; ++i) acc += As[ty][i] * Bs[tx][i];
    __syncthreads();
  }
  acc = fmaxf(acc + bias[n], 0.f);
  if (OUT_BF16) outB[(size_t)r * N + n] = __float2bfloat16(acc);
  else          outF[(size_t)r * N + n] = acc;
}

// ---------------- fp32 -> bf16 weight convert with row pad to NP4 ----------------
__global__ void cvt_o_k(const float* __restrict__ Wsrc, bf16* __restrict__ Wb) {
  const size_t idx = ((size_t)blockIdx.x * 256 + threadIdx.x) * 4;  // < NP4*512
  const int e = (int)(idx >> 9);
  ushort4 o;
  if (e < IND) {
    f32x4 v = *(const f32x4*)(Wsrc + idx);
    o.x = f2bfu(v[0]); o.y = f2bfu(v[1]); o.z = f2bfu(v[2]); o.w = f2bfu(v[3]);
  } else {
    o.x = 0; o.y = 0; o.z = 0; o.w = 0;
  }
  *(ushort4*)((u16*)Wb + idx) = o;
}

extern "C" void kernel_launch(void* const* d_in, const int* in_sizes, int n_in,
                              void* d_out, int out_size, void* d_ws, size_t ws_size,
                              hipStream_t stream) {
  const float* x     = (const float*)d_in[0];
  const float* bn0_g = (const float*)d_in[1];
  const float* bn0_b = (const float*)d_in[2];
  const float* enc_W = (const float*)d_in[3];
  const float* enc_b = (const float*)d_in[4];
  const float* bn1_g = (const float*)d_in[5];
  const float* bn1_b = (const float*)d_in[6];
  const float* bot_W = (const float*)d_in[7];
  const float* bot_b = (const float*)d_in[8];
  const float* bn2_g = (const float*)d_in[9];
  const float* bn2_b = (const float*)d_in[10];
  const float* dec_W = (const float*)d_in[11];
  const float* dec_b = (const float*)d_in[12];
  const float* o1_W  = (const float*)d_in[13];
  const float* o1_b  = (const float*)d_in[14];
  const float* o2_W  = (const float*)d_in[15];
  const float* o2_b  = (const float*)d_in[16];
  const float* o3_W  = (const float*)d_in[17];
  const float* o3_b  = (const float*)d_in[18];

  char* wsb = (char*)d_ws;
  size_t off = 0;
  auto alloc = [&](size_t bytes) -> void* {
    void* p = wsb + off;
    off = (off + bytes + 255) & ~(size_t)255;
    return p;
  };
  float* row_sum = (float*)alloc(B_ * 4);
  float* sArr    = (float*)alloc(B_ * 4);
  float* invs    = (float*)alloc(B_ * 4);
  float* scale0  = (float*)alloc(IND * 4);
  float* shift0  = (float*)alloc(IND * 4);
  float* bias1   = (float*)alloc(ENCN * 4);
  float* scale1  = (float*)alloc(ENCN * 4);
  float* shift1  = (float*)alloc(ENCN * 4);
  float* scale2  = (float*)alloc(BOTN * 4);
  float* shift2  = (float*)alloc(BOTN * 4);
  float* C1      = (float*)alloc((size_t)B_ * ENCN * 4);
  float* C2      = (float*)alloc((size_t)B_ * BOTN * 4);
  float* Cp      = (float*)alloc((size_t)SPLITK * B_ * ENCN * 4);
  bf16*  L       = (bf16*)alloc((size_t)B_ * KP1 * 2);
  bf16*  Wp      = (bf16*)alloc((size_t)ENCN * KP1 * 2);
  bf16*  h3      = (bf16*)alloc((size_t)B_ * DECN * 2);
  bf16*  wbf0    = (bf16*)alloc((size_t)NP4 * 512 * 2);
  bf16*  wbf1    = (bf16*)alloc((size_t)NP4 * 512 * 2);
  bf16*  wbf2    = (bf16*)alloc((size_t)NP4 * 512 * 2);
  // BN0 partials alias Cp (disjoint lifetime: dead before GEMM1 writes Cp)
  float* part_s  = Cp;
  float* part_q  = Cp + (size_t)64 * KP1;

  // 1. row sums + median scales
  rowsum_k<<<B_, 256, 0, stream>>>(x, row_sum);
  median_scale_k<<<1, 1024, 0, stream>>>(row_sum, sArr, invs);

  // 2. L = bf16(log1p(x/s)), BN0 stats (partial sums, no atomics)
  pass2_k<<<dim3(KP1 / 1024, 64), 256, 0, stream>>>(x, invs, L, part_s, part_q);
  finalize_bn_k<<<(IND + 255) / 256, 256, 0, stream>>>(part_s, part_q, bn0_g, bn0_b,
                                                       scale0, shift0);

  // 3. fold BN0 into encoder weights
  prepw_k<<<ENCN, 256, 0, stream>>>(enc_W, enc_b, scale0, shift0, Wp, bias1);

  // 4. GEMM1 (split-K=8) + reduce(+bias+relu) -> C1
  gemm_bt<0><<<dim3(B_ / 128, ENCN / 128, SPLITK), 256, 0, stream>>>(
      L, Wp, KP1, KSTEP1, Cp, nullptr, nullptr, nullptr, ENCN, ENCN);
  reduce1_k<<<(B_ * ENCN) / 1024, 256, 0, stream>>>(Cp, bias1, C1);

  // 5. BN1 -> GEMM2 -> C2; BN2 -> GEMM3 -> h3 (bf16)
  colstats_k<<<ENCN / 64, 256, 0, stream>>>(C1, B_, ENCN, bn1_g, bn1_b, scale1, shift1);
  gemm_small<false><<<dim3(B_ / 16, BOTN / 16), dim3(16, 16), 0, stream>>>(
      C1, scale1, shift1, bot_W, bot_b, C2, nullptr, B_, BOTN, ENCN);
  colstats_k<<<BOTN / 64, 256, 0, stream>>>(C2, B_, BOTN, bn2_g, bn2_b, scale2, shift2);
  gemm_small<true><<<dim3(B_ / 16, DECN / 16), dim3(16, 16), 0, stream>>>(
      C2, scale2, shift2, dec_W, dec_b, nullptr, h3, B_, DECN, BOTN);

  // 6. convert output weights to bf16 (padded rows = 0)
  const int cvtg = (NP4 * 512) / 1024;
  cvt_o_k<<<cvtg, 256, 0, stream>>>(o1_W, wbf0);
  cvt_o_k<<<cvtg, 256, 0, stream>>>(o2_W, wbf1);
  cvt_o_k<<<cvtg, 256, 0, stream>>>(o3_W, wbf2);

  // 7. output GEMMs with fused epilogues
  float* out = (float*)d_out;
  const size_t OFF = (size_t)B_ * IND;
  // pai = sigmoid(h3 @ o2_W.T + o2_b)
  gemm_bt<1><<<dim3(B_ / 128, NP4 / 128), 256, 0, stream>>>(
      h3, wbf1, 512, 8, out, nullptr, o2_b, nullptr, IND, IND);
  // M = exp(h3 @ o1_W.T + o1_b), M_loss = s * M
  gemm_bt<2><<<dim3(B_ / 128, NP4 / 128), 256, 0, stream>>>(
      h3, wbf0, 512, 8, out + OFF, out + 3 * OFF, o1_b, sArr, IND, IND);
  // theta = exp(h3 @ o3_W.T + o3_b)
  gemm_bt<3><<<dim3(B_ / 128, NP4 / 128), 256, 0, stream>>>(
      h3, wbf2, 512, 8, out + 2 * OFF, nullptr, o3_b, nullptr, IND, IND);
}

// Round 3
// 677.060 us; speedup vs baseline: 1.5388x; 1.4682x over previous
//
#include <hip/hip_runtime.h>
#include <hip/hip_bf16.h>
#include <math.h>

#define B_    2048
#define IND   20000
#define ENCN  512
#define BOTN  128
#define DECN  512
#define KP1   20480   // IND padded to 64*320
#define NP    20224   // IND padded to 79*256
#define SPLITK 16
#define KSTEP1 20     // 16*20*64 = 20480
#define BNEPS 1e-5f

typedef __hip_bfloat16 bf16;
typedef __bf16 bf16x8 __attribute__((ext_vector_type(8)));
typedef float f32x4 __attribute__((ext_vector_type(4)));
typedef unsigned short u16;

__device__ __forceinline__ u16 f2bfu(float f) {
  __hip_bfloat16 h = __float2bfloat16(f);
  return *reinterpret_cast<u16*>(&h);
}

__device__ __forceinline__ void gload_lds16(const bf16* g, bf16* l) {
  __builtin_amdgcn_global_load_lds(
      (const __attribute__((address_space(1))) void*)g,
      (__attribute__((address_space(3))) void*)l, 16, 0, 0);
}

// ---------------- row sums ----------------
__global__ void rowsum_k(const float* __restrict__ x, float* __restrict__ row_sum) {
  const int row = blockIdx.x;
  const f32x4* xr = (const f32x4*)(x + (size_t)row * IND);
  float s = 0.f;
  for (int i = threadIdx.x; i < IND / 4; i += 256) {
    f32x4 v = xr[i];
    s += (v[0] + v[1]) + (v[2] + v[3]);
  }
#pragma unroll
  for (int o = 32; o > 0; o >>= 1) s += __shfl_down(s, o, 64);
  __shared__ float ws4[4];
  if ((threadIdx.x & 63) == 0) ws4[threadIdx.x >> 6] = s;
  __syncthreads();
  if (threadIdx.x == 0) row_sum[row] = (ws4[0] + ws4[1]) + (ws4[2] + ws4[3]);
}

// ---------------- median + per-row scale ----------------
__global__ void median_scale_k(const float* __restrict__ row_sum,
                               float* __restrict__ sArr, float* __restrict__ invs) {
  __shared__ float v[B_];
  const int tid = threadIdx.x;  // 1024 threads
  v[tid] = row_sum[tid];
  v[tid + 1024] = row_sum[tid + 1024];
  __syncthreads();
  for (int k = 2; k <= B_; k <<= 1) {
    for (int j = k >> 1; j > 0; j >>= 1) {
      for (int i = tid; i < B_; i += 1024) {
        int ixj = i ^ j;
        if (ixj > i) {
          bool up = ((i & k) == 0);
          float a = v[i], b = v[ixj];
          if ((a > b) == up) { v[i] = b; v[ixj] = a; }
        }
      }
      __syncthreads();
    }
  }
  float med = 0.5f * (v[B_ / 2 - 1] + v[B_ / 2]);
  for (int i = tid; i < B_; i += 1024) {
    float rs = row_sum[i];
    sArr[i] = rs / med;
    invs[i] = med / rs;
  }
}

// ---------------- pass2: L = bf16(log1p(x*invs)), partial col sums/sumsq ----------------
__global__ void pass2_k(const float* __restrict__ x, const float* __restrict__ invs,
                        bf16* __restrict__ L, float* __restrict__ part_s,
                        float* __restrict__ part_q) {
  const int c0 = (blockIdx.x * 256 + threadIdx.x) * 4;   // 0..20476
  const int rblk = blockIdx.y;
  const int r0 = rblk * 32;
  const bool valid = (c0 < IND);
  f32x4 sum = {0.f, 0.f, 0.f, 0.f}, sq = {0.f, 0.f, 0.f, 0.f};
  for (int r = r0; r < r0 + 32; ++r) {
    f32x4 lv = {0.f, 0.f, 0.f, 0.f};
    if (valid) {
      f32x4 v = *(const f32x4*)(x + (size_t)r * IND + c0);
      float iv = invs[r];
      lv[0] = log1pf(v[0] * iv); lv[1] = log1pf(v[1] * iv);
      lv[2] = log1pf(v[2] * iv); lv[3] = log1pf(v[3] * iv);
      sum += lv; sq += lv * lv;
    }
    ushort4 o;
    o.x = f2bfu(lv[0]); o.y = f2bfu(lv[1]); o.z = f2bfu(lv[2]); o.w = f2bfu(lv[3]);
    *(ushort4*)((u16*)L + (size_t)r * KP1 + c0) = o;
  }
  if (valid) {
    *(f32x4*)(part_s + (size_t)rblk * KP1 + c0) = sum;
    *(f32x4*)(part_q + (size_t)rblk * KP1 + c0) = sq;
  }
}

// ---------------- finalize BN0 from 64 partials ----------------
__global__ void finalize_bn_k(const float* __restrict__ part_s, const float* __restrict__ part_q,
                              const float* __restrict__ g, const float* __restrict__ b,
                              float* __restrict__ scale, float* __restrict__ shift) {
  int c = blockIdx.x * 256 + threadIdx.x;
  if (c >= IND) return;
  float s = 0.f, q = 0.f;
  for (int z = 0; z < 64; ++z) {
    s += part_s[(size_t)z * KP1 + c];
    q += part_q[(size_t)z * KP1 + c];
  }
  const float invN = 1.f / (float)B_;
  float mean = s * invN;
  float var = q * invN - mean * mean;
  float sc = g[c] * rsqrtf(var + BNEPS);
  scale[c] = sc;
  shift[c] = b[c] - mean * sc;
}

// ---------------- W' = bf16(enc_W * scale0), bias1 = enc_b + shift0 . enc_W^T ----------------
__global__ void prepw_k(const float* __restrict__ encW, const float* __restrict__ enc_b,
                        const float* __restrict__ scale0, const float* __restrict__ shift0,
                        bf16* __restrict__ Wp, float* __restrict__ bias1) {
  const int e = blockIdx.x;  // 512
  float local = 0.f;
  for (int j0 = threadIdx.x * 4; j0 < KP1; j0 += 1024) {
    ushort4 o;
    if (j0 < IND) {
      f32x4 w = *(const f32x4*)(encW + (size_t)e * IND + j0);
      f32x4 sc = *(const f32x4*)(scale0 + j0);
      f32x4 sh = *(const f32x4*)(shift0 + j0);
      local += sh[0] * w[0] + sh[1] * w[1] + sh[2] * w[2] + sh[3] * w[3];
      o.x = f2bfu(w[0] * sc[0]); o.y = f2bfu(w[1] * sc[1]);
      o.z = f2bfu(w[2] * sc[2]); o.w = f2bfu(w[3] * sc[3]);
    } else {
      o.x = 0; o.y = 0; o.z = 0; o.w = 0;
    }
    *(ushort4*)((u16*)Wp + (size_t)e * KP1 + j0) = o;
  }
#pragma unroll
  for (int o = 32; o > 0; o >>= 1) local += __shfl_down(local, o, 64);
  __shared__ float red[4];
  if ((threadIdx.x & 63) == 0) red[threadIdx.x >> 6] = local;
  __syncthreads();
  if (threadIdx.x == 0) bias1[e] = enc_b[e] + ((red[0] + red[1]) + (red[2] + red[3]));
}

// ---------------- 256x256 8-wave 2-phase dbuf GEMM (m201 geometry), XCD-swizzled ----------------
// A[M][Kpad] bf16, B[N][Kpad] bf16, C = A.B^T
// MODE 0: split-K f32x4 partial (GEMM1); 1: sigmoid; 2: exp + s*exp dual; 3: exp
template <int MODE>
__global__ __launch_bounds__(512, 2)
void gemm256(const bf16* __restrict__ A, const bf16* __restrict__ Bm,
             int Kpad, int ksteps,
             float* __restrict__ out0, float* __restrict__ out1,
             const float* __restrict__ bias, const float* __restrict__ sArr,
             int ldo, int Nlimit) {
  extern __shared__ __align__(16) bf16 smem[];  // 128 KiB
  bf16* AsB = smem;           // [2][16384]
  bf16* BsB = smem + 32768;   // [2][16384]
  const int tid = threadIdx.x;
  const int lane = tid & 63;
  const int wave = tid >> 6;      // 0..7
  const int wr = wave >> 2;       // M half
  const int wc = wave & 3;        // N quarter

  // chunked XCD swizzle (nwg % 8 == 0 for all our grids)
  const int nwg = gridDim.x;
  const int q8 = nwg >> 3;
  const int bid = blockIdx.x;
  const int swz = (bid & 7) * q8 + (bid >> 3);
  const int xm = swz & 7;
  const int rest = swz >> 3;
  int yn, z;
  if (MODE == 0) { yn = rest & 1; z = rest >> 1; } else { yn = rest; z = 0; }
  const int m0 = xm * 256;
  const int n0 = yn * 256;
  const int kbeg = z * ksteps * 64;

  // staging: thread t, chunk i in 0..3 stages row i*64 + (t>>3), logical chunk
  // (t&7)^(row&7) (both-sides swizzle: linear LDS dest + pre-swizzled source).
  const int srow = tid >> 3;                    // 0..63
  const int schunk = (tid & 7) ^ (srow & 7);
  const bf16* gA = A + (size_t)(m0 + srow) * Kpad + kbeg + schunk * 8;
  const bf16* gB = Bm + (size_t)(n0 + srow) * Kpad + kbeg + schunk * 8;
  const int ldst = tid * 8;                     // elt offset within 4096-elt group

  f32x4 acc[8][4] = {};
  const int lrow = lane & 15;
  const int kq = lane >> 4;   // 0..3

  auto STAGE = [&](int ks, int buf) {
    const bf16* ga = gA + (size_t)ks * 64;
    const bf16* gb = gB + (size_t)ks * 64;
    bf16* la = AsB + buf * 16384 + ldst;
    bf16* lb = BsB + buf * 16384 + ldst;
#pragma unroll
    for (int i = 0; i < 4; ++i) {
      gload_lds16(ga + (size_t)(i * 64) * Kpad, la + i * 4096);
      gload_lds16(gb + (size_t)(i * 64) * Kpad, lb + i * 4096);
    }
  };

  STAGE(0, 0);
  asm volatile("s_waitcnt vmcnt(0)" ::: "memory");
  __builtin_amdgcn_s_barrier();

  int cur = 0;
  for (int ks = 0; ks < ksteps; ++ks) {
    if (ks + 1 < ksteps) STAGE(ks + 1, cur ^ 1);
    const bf16* As = AsB + cur * 16384;
    const bf16* Bs = BsB + cur * 16384;
#pragma unroll
    for (int kk = 0; kk < 2; ++kk) {
      const int kc = kk * 4 + kq;
      bf16x8 af[8], bfv[4];
#pragma unroll
      for (int m = 0; m < 8; ++m) {
        const int row = wr * 128 + m * 16 + lrow;
        af[m] = *(const bf16x8*)(&As[row * 64 + ((kc ^ (row & 7)) << 3)]);
      }
#pragma unroll
      for (int n = 0; n < 4; ++n) {
        const int row = wc * 64 + n * 16 + lrow;
        bfv[n] = *(const bf16x8*)(&Bs[row * 64 + ((kc ^ (row & 7)) << 3)]);
      }
#pragma unroll
      for (int m = 0; m < 8; ++m)
#pragma unroll
        for (int n = 0; n < 4; ++n)
          // swapped operands: lane holds C[m_base+(lane&15)][n_base+(lane>>4)*4+reg]
          acc[m][n] = __builtin_amdgcn_mfma_f32_16x16x32_bf16(bfv[n], af[m], acc[m][n], 0, 0, 0);
    }
    if (ks + 1 < ksteps) {
      asm volatile("s_waitcnt vmcnt(0)" ::: "memory");
      __builtin_amdgcn_s_barrier();
      cur ^= 1;
    }
  }

  float* o0 = out0;
  if (MODE == 0) o0 += (size_t)z * ((size_t)B_ * ldo);
  const int growb = m0 + wr * 128 + lrow;
  const int gcolb = n0 + wc * 64 + kq * 4;
#pragma unroll
  for (int m = 0; m < 8; ++m) {
    const int grow = growb + m * 16;
    float srow_s = 0.f;
    if (MODE == 2) srow_s = sArr[grow];
#pragma unroll
    for (int n = 0; n < 4; ++n) {
      const int gcol = gcolb + n * 16;
      f32x4 v = acc[m][n];
      if (MODE == 0) {
        *(f32x4*)(&o0[(size_t)grow * ldo + gcol]) = v;
      } else if (gcol < Nlimit) {
        f32x4 bb = *(const f32x4*)(&bias[gcol]);
        f32x4 t = v + bb;
        f32x4 r;
        if (MODE == 1) {
#pragma unroll
          for (int j = 0; j < 4; ++j) r[j] = 1.f / (1.f + __expf(-t[j]));
          *(f32x4*)(&o0[(size_t)grow * ldo + gcol]) = r;
        } else if (MODE == 2) {
#pragma unroll
          for (int j = 0; j < 4; ++j) r[j] = __expf(t[j]);
          *(f32x4*)(&o0[(size_t)grow * ldo + gcol]) = r;
          f32x4 rl;
#pragma unroll
          for (int j = 0; j < 4; ++j) rl[j] = srow_s * r[j];
          *(f32x4*)(&out1[(size_t)grow * ldo + gcol]) = rl;
        } else {
#pragma unroll
          for (int j = 0; j < 4; ++j) r[j] = __expf(t[j]);
          *(f32x4*)(&o0[(size_t)grow * ldo + gcol]) = r;
        }
      }
    }
  }
}

// ---------------- 128x128 4-wave GEMM for small layers (bias+relu epilogues) ----------------
// MODE 4: f32 out; MODE 5: bf16 out
template <int MODE>
__global__ __launch_bounds__(256, 2)
void gemm128(const bf16* __restrict__ A, const bf16* __restrict__ Bm,
             int Kpad, int ksteps,
             float* __restrict__ outF, bf16* __restrict__ outB,
             const float* __restrict__ bias, int ldo) {
  __shared__ __align__(16) bf16 As[2][128 * 64];
  __shared__ __align__(16) bf16 Bs[2][128 * 64];
  const int tid = threadIdx.x;
  const int wave = tid >> 6;
  const int lane = tid & 63;
  const int wr = wave >> 1, wc = wave & 1;
  const int m0 = blockIdx.x * 128;
  const int n0 = blockIdx.y * 128;

  const int srow = wave * 32 + (lane >> 3);
  const int scol = ((lane & 7) ^ (lane >> 3)) * 8;
  const bf16* gA = A + (size_t)(m0 + srow) * Kpad + scol;
  const bf16* gB = Bm + (size_t)(n0 + srow) * Kpad + scol;
  const int lbase = wave * 2048;

  f32x4 acc[4][4] = {};
  const int lrow = lane & 15;
  const int swz = lrow & 7;
  const int kq = lane >> 4;

  auto STAGE = [&](int ks, int buf) {
    const bf16* ga = gA + (size_t)ks * 64;
    const bf16* gb = gB + (size_t)ks * 64;
#pragma unroll
    for (int i = 0; i < 4; ++i) {
      gload_lds16(ga + (size_t)(i * 8) * Kpad, &As[buf][lbase + i * 512]);
      gload_lds16(gb + (size_t)(i * 8) * Kpad, &Bs[buf][lbase + i * 512]);
    }
  };

  STAGE(0, 0);
  asm volatile("s_waitcnt vmcnt(0)" ::: "memory");
  __builtin_amdgcn_s_barrier();

  int cur = 0;
  for (int ks = 0; ks < ksteps; ++ks) {
    if (ks + 1 < ksteps) STAGE(ks + 1, cur ^ 1);
#pragma unroll
    for (int kk = 0; kk < 2; ++kk) {
      const int kc = kk * 4 + kq;
      bf16x8 af[4], bfv[4];
#pragma unroll
      for (int m = 0; m < 4; ++m) {
        const int row = wr * 64 + m * 16 + lrow;
        af[m] = *(const bf16x8*)(&As[cur][row * 64 + (((kc ^ swz) & 7) << 3)]);
      }
#pragma unroll
      for (int n = 0; n < 4; ++n) {
        const int row = wc * 64 + n * 16 + lrow;
        bfv[n] = *(const bf16x8*)(&Bs[cur][row * 64 + (((kc ^ swz) & 7) << 3)]);
      }
#pragma unroll
      for (int m = 0; m < 4; ++m)
#pragma unroll
        for (int n = 0; n < 4; ++n)
          acc[m][n] = __builtin_amdgcn_mfma_f32_16x16x32_bf16(bfv[n], af[m], acc[m][n], 0, 0, 0);
    }
    if (ks + 1 < ksteps) {
      asm volatile("s_waitcnt vmcnt(0)" ::: "memory");
      __builtin_amdgcn_s_barrier();
      cur ^= 1;
    }
  }

  const int growb = m0 + wr * 64 + lrow;
  const int gcolb = n0 + wc * 64 + kq * 4;
#pragma unroll
  for (int m = 0; m < 4; ++m) {
    const int grow = growb + m * 16;
#pragma unroll
    for (int n = 0; n < 4; ++n) {
      const int gcol = gcolb + n * 16;
      f32x4 bb = *(const f32x4*)(&bias[gcol]);
      f32x4 t = acc[m][n] + bb;
      if (MODE == 4) {
        f32x4 r;
#pragma unroll
        for (int j = 0; j < 4; ++j) r[j] = fmaxf(t[j], 0.f);
        *(f32x4*)(&outF[(size_t)grow * ldo + gcol]) = r;
      } else {
        ushort4 o;
        o.x = f2bfu(fmaxf(t[0], 0.f)); o.y = f2bfu(fmaxf(t[1], 0.f));
        o.z = f2bfu(fmaxf(t[2], 0.f)); o.w = f2bfu(fmaxf(t[3], 0.f));
        *(ushort4*)((u16*)outB + (size_t)grow * ldo + gcol) = o;
      }
    }
  }
}

// ---------------- split-K reduce + bias + relu -> C1 ----------------
__global__ void reduce1_k(const float* __restrict__ Cp, const float* __restrict__ bias1,
                          float* __restrict__ C1) {
  const size_t i4 = ((size_t)blockIdx.x * 256 + threadIdx.x) * 4;
  f32x4 t = {0.f, 0.f, 0.f, 0.f};
#pragma unroll
  for (int z = 0; z < SPLITK; ++z) t += *(const f32x4*)(Cp + (size_t)z * (B_ * ENCN) + i4);
  f32x4 bb = *(const f32x4*)(bias1 + (i4 & (ENCN - 1)));
  t += bb;
  f32x4 r;
#pragma unroll
  for (int j = 0; j < 4; ++j) r[j] = fmaxf(t[j], 0.f);
  *(f32x4*)(C1 + i4) = r;
}

// ---------------- column stats, 2-stage ----------------
__global__ void colpart_k(const float* __restrict__ X, int C,
                          float* __restrict__ ps, float* __restrict__ pq) {
  const int cl = threadIdx.x & 63;
  const int rg = threadIdx.x >> 6;
  const int c = blockIdx.x * 64 + cl;
  const int r0 = blockIdx.y * 64 + rg * 16;
  float sum = 0.f, sq = 0.f;
  for (int rr = 0; rr < 16; ++rr) {
    float v = X[(size_t)(r0 + rr) * C + c];
    sum += v; sq += v * v;
  }
  __shared__ float ls[4][64], lq[4][64];
  ls[rg][cl] = sum; lq[rg][cl] = sq;
  __syncthreads();
  if (rg == 0) {
    sum = (ls[0][cl] + ls[1][cl]) + (ls[2][cl] + ls[3][cl]);
    sq = (lq[0][cl] + lq[1][cl]) + (lq[2][cl] + lq[3][cl]);
    ps[(size_t)blockIdx.y * C + c] = sum;
    pq[(size_t)blockIdx.y * C + c] = sq;
  }
}

__global__ void colfin_k(const float* __restrict__ ps, const float* __restrict__ pq,
                         const float* __restrict__ g, const float* __restrict__ b,
                         float* __restrict__ scale, float* __restrict__ shift, int C) {
  int c = blockIdx.x * 256 + threadIdx.x;
  if (c >= C) return;
  float sum = 0.f, sq = 0.f;
  for (int z = 0; z < 32; ++z) {
    sum += ps[(size_t)z * C + c];
    sq += pq[(size_t)z * C + c];
  }
  const float invN = 1.f / (float)B_;
  float mean = sum * invN;
  float var = sq * invN - mean * mean;
  float sc = g[c] * rsqrtf(var + BNEPS);
  scale[c] = sc;
  shift[c] = b[c] - mean * sc;
}

// ---------------- affine (BN) + bf16 cvt ----------------
__global__ void affine_k(const float* __restrict__ X, const float* __restrict__ sc,
                         const float* __restrict__ sh, bf16* __restrict__ out, int Cm1) {
  const size_t i4 = ((size_t)blockIdx.x * 256 + threadIdx.x) * 4;
  const int c0 = (int)(i4 & (size_t)Cm1);
  f32x4 v = *(const f32x4*)(X + i4);
  f32x4 s = *(const f32x4*)(sc + c0);
  f32x4 h = *(const f32x4*)(sh + c0);
  f32x4 t = v * s + h;
  ushort4 o;
  o.x = f2bfu(t[0]); o.y = f2bfu(t[1]); o.z = f2bfu(t[2]); o.w = f2bfu(t[3]);
  *(ushort4*)((u16*)out + i4) = o;
}

// ---------------- plain f32 -> bf16 cvt ----------------
__global__ void cvtw_k(const float* __restrict__ src, bf16* __restrict__ dst) {
  const size_t i4 = ((size_t)blockIdx.x * 256 + threadIdx.x) * 4;
  f32x4 v = *(const f32x4*)(src + i4);
  ushort4 o;
  o.x = f2bfu(v[0]); o.y = f2bfu(v[1]); o.z = f2bfu(v[2]); o.w = f2bfu(v[3]);
  *(ushort4*)((u16*)dst + i4) = o;
}

// ---------------- output weight cvt with row pad to NP ----------------
__global__ void cvt_o_k(const float* __restrict__ Wsrc, bf16* __restrict__ Wb) {
  const size_t idx = ((size_t)blockIdx.x * 256 + threadIdx.x) * 4;  // < NP*512
  const int e = (int)(idx >> 9);
  ushort4 o;
  if (e < IND) {
    f32x4 v = *(const f32x4*)(Wsrc + idx);
    o.x = f2bfu(v[0]); o.y = f2bfu(v[1]); o.z = f2bfu(v[2]); o.w = f2bfu(v[3]);
  } else {
    o.x = 0; o.y = 0; o.z = 0; o.w = 0;
  }
  *(ushort4*)((u16*)Wb + idx) = o;
}

extern "C" void kernel_launch(void* const* d_in, const int* in_sizes, int n_in,
                              void* d_out, int out_size, void* d_ws, size_t ws_size,
                              hipStream_t stream) {
  const float* x     = (const float*)d_in[0];
  const float* bn0_g = (const float*)d_in[1];
  const float* bn0_b = (const float*)d_in[2];
  const float* enc_W = (const float*)d_in[3];
  const float* enc_b = (const float*)d_in[4];
  const float* bn1_g = (const float*)d_in[5];
  const float* bn1_b = (const float*)d_in[6];
  const float* bot_W = (const float*)d_in[7];
  const float* bot_b = (const float*)d_in[8];
  const float* bn2_g = (const float*)d_in[9];
  const float* bn2_b = (const float*)d_in[10];
  const float* dec_W = (const float*)d_in[11];
  const float* dec_b = (const float*)d_in[12];
  const float* o1_W  = (const float*)d_in[13];
  const float* o1_b  = (const float*)d_in[14];
  const float* o2_W  = (const float*)d_in[15];
  const float* o2_b  = (const float*)d_in[16];
  const float* o3_W  = (const float*)d_in[17];
  const float* o3_b  = (const float*)d_in[18];

  char* wsb = (char*)d_ws;
  size_t off = 0;
  auto alloc = [&](size_t bytes) -> void* {
    void* p = wsb + off;
    off = (off + bytes + 255) & ~(size_t)255;
    return p;
  };
  float* row_sum = (float*)alloc(B_ * 4);
  float* sArr    = (float*)alloc(B_ * 4);
  float* invs    = (float*)alloc(B_ * 4);
  float* scale0  = (float*)alloc(IND * 4);
  float* shift0  = (float*)alloc(IND * 4);
  float* bias1   = (float*)alloc(ENCN * 4);
  float* scale1  = (float*)alloc(ENCN * 4);
  float* shift1  = (float*)alloc(ENCN * 4);
  float* scale2  = (float*)alloc(BOTN * 4);
  float* shift2  = (float*)alloc(BOTN * 4);
  float* ps1     = (float*)alloc(32 * ENCN * 4);
  float* pq1     = (float*)alloc(32 * ENCN * 4);
  float* ps2     = (float*)alloc(32 * BOTN * 4);
  float* pq2     = (float*)alloc(32 * BOTN * 4);
  float* C1      = (float*)alloc((size_t)B_ * ENCN * 4);
  float* C2f     = (float*)alloc((size_t)B_ * BOTN * 4);
  float* Cp      = (float*)alloc((size_t)SPLITK * B_ * ENCN * 4);
  bf16*  L       = (bf16*)alloc((size_t)B_ * KP1 * 2);
  bf16*  Wp      = (bf16*)alloc((size_t)ENCN * KP1 * 2);
  bf16*  A1b     = (bf16*)alloc((size_t)B_ * ENCN * 2);
  bf16*  A2b     = (bf16*)alloc((size_t)B_ * BOTN * 2);
  bf16*  botWb   = (bf16*)alloc((size_t)BOTN * ENCN * 2);
  bf16*  decWb   = (bf16*)alloc((size_t)DECN * BOTN * 2);
  bf16*  h3      = (bf16*)alloc((size_t)B_ * DECN * 2);
  bf16*  wbf0    = (bf16*)alloc((size_t)NP * 512 * 2);
  bf16*  wbf1    = (bf16*)alloc((size_t)NP * 512 * 2);
  bf16*  wbf2    = (bf16*)alloc((size_t)NP * 512 * 2);
  // BN0 partials alias Cp (dead before GEMM1 writes Cp)
  float* part_s  = Cp;
  float* part_q  = Cp + (size_t)64 * KP1;

  // enable 128 KiB dynamic LDS for the 256^2 GEMM (idempotent host-side call)
  hipFuncSetAttribute(reinterpret_cast<const void*>(gemm256<0>),
                      hipFuncAttributeMaxDynamicSharedMemorySize, 131072);
  hipFuncSetAttribute(reinterpret_cast<const void*>(gemm256<1>),
                      hipFuncAttributeMaxDynamicSharedMemorySize, 131072);
  hipFuncSetAttribute(reinterpret_cast<const void*>(gemm256<2>),
                      hipFuncAttributeMaxDynamicSharedMemorySize, 131072);
  hipFuncSetAttribute(reinterpret_cast<const void*>(gemm256<3>),
                      hipFuncAttributeMaxDynamicSharedMemorySize, 131072);

  // 1. row sums + median scales
  rowsum_k<<<B_, 256, 0, stream>>>(x, row_sum);
  median_scale_k<<<1, 1024, 0, stream>>>(row_sum, sArr, invs);

  // 2. L = bf16(log1p(x/s)), BN0 stats
  pass2_k<<<dim3(KP1 / 1024, 64), 256, 0, stream>>>(x, invs, L, part_s, part_q);
  finalize_bn_k<<<(IND + 255) / 256, 256, 0, stream>>>(part_s, part_q, bn0_g, bn0_b,
                                                       scale0, shift0);

  // 3. fold BN0 into encoder weights
  prepw_k<<<ENCN, 256, 0, stream>>>(enc_W, enc_b, scale0, shift0, Wp, bias1);

  // 4. GEMM1 (256^2, split-K=16) + reduce(+bias+relu) -> C1
  gemm256<0><<<8 * 2 * SPLITK, 512, 131072, stream>>>(
      L, Wp, KP1, KSTEP1, Cp, nullptr, nullptr, nullptr, ENCN, ENCN);
  reduce1_k<<<(B_ * ENCN) / 1024, 256, 0, stream>>>(Cp, bias1, C1);

  // 5. BN1 -> GEMM2 (MFMA) -> C2; BN2 -> GEMM3 (MFMA) -> h3 bf16
  colpart_k<<<dim3(ENCN / 64, 32), 256, 0, stream>>>(C1, ENCN, ps1, pq1);
  colfin_k<<<2, 256, 0, stream>>>(ps1, pq1, bn1_g, bn1_b, scale1, shift1, ENCN);
  affine_k<<<(B_ * ENCN) / 1024, 256, 0, stream>>>(C1, scale1, shift1, A1b, ENCN - 1);
  cvtw_k<<<(BOTN * ENCN) / 1024, 256, 0, stream>>>(bot_W, botWb);
  gemm128<4><<<dim3(16, 1), 256, 0, stream>>>(A1b, botWb, ENCN, ENCN / 64,
                                              C2f, nullptr, bot_b, BOTN);
  colpart_k<<<dim3(BOTN / 64, 32), 256, 0, stream>>>(C2f, BOTN, ps2, pq2);
  colfin_k<<<1, 256, 0, stream>>>(ps2, pq2, bn2_g, bn2_b, scale2, shift2, BOTN);
  affine_k<<<(B_ * BOTN) / 1024, 256, 0, stream>>>(C2f, scale2, shift2, A2b, BOTN - 1);
  cvtw_k<<<(DECN * BOTN) / 1024, 256, 0, stream>>>(dec_W, decWb);
  gemm128<5><<<dim3(16, 4), 256, 0, stream>>>(A2b, decWb, BOTN, BOTN / 64,
                                              nullptr, h3, dec_b, DECN);

  // 6. convert output weights to bf16 (padded rows = 0)
  const int cvtg = (NP * 512) / 1024;
  cvt_o_k<<<cvtg, 256, 0, stream>>>(o1_W, wbf0);
  cvt_o_k<<<cvtg, 256, 0, stream>>>(o2_W, wbf1);
  cvt_o_k<<<cvtg, 256, 0, stream>>>(o3_W, wbf2);

  // 7. output GEMMs (256^2) with fused epilogues
  float* out = (float*)d_out;
  const size_t OFF = (size_t)B_ * IND;
  const int onwg = 8 * (NP / 256);  // 632, divisible by 8
  gemm256<1><<<onwg, 512, 131072, stream>>>(
      h3, wbf1, 512, 8, out, nullptr, o2_b, nullptr, IND, IND);
  gemm256<2><<<onwg, 512, 131072, stream>>>(
      h3, wbf0, 512, 8, out + OFF, out + 3 * OFF, o1_b, sArr, IND, IND);
  gemm256<3><<<onwg, 512, 131072, stream>>>(
      h3, wbf2, 512, 8, out + 2 * OFF, nullptr, o3_b, nullptr, IND, IND);
}